// Round 12
// baseline (467.290 us; speedup 1.0000x reference)
//
#include <hip/hip_runtime.h>
#include <hip/hip_bf16.h>

// GCN encoder: h = relu(Agg(h @ W)) x3 after input linear.
// N=20000 nodes, E=640000 edges, H=128.
// R1->R2: CSR pull-agg replaced atomics (3330->367us).
// R2->R3..R6: GEMM evolution (367->282us).
// R6->R7: GEMMs on matrix pipe via 3-term bf16 split (245us).
// R8->R9: bf16 payload + 2-slice L2-resident agg (FETCH 107->20.5MB).
// R9->R10: de-LDS'd index arrays (197us). R10->R11: MLP boost ~neutral (193)
//         -> agg is L2-random-BW-bound (~7TB/s), not latency-bound.
// R11->R12: (1) LDS-staged agg: xwb stored colpair-major [64][N][2]; block
//         stages 4 cols x all N nodes (160KB LDS), 2 nodes/wave, coalesced
//         csr loads + shfl distribution, payload from LDS -> no L2 gather.
//         (2) 4-way split CSR counters off4[v*4 + e&3]: quarters per-address
//         atomic contention in count/fill (suspected ~60us combined).
// ws layout: [dis: N f][off4: 4N i][csr: E i][hh: N*128 bf16][hl: N*128 bf16]
//            [xwb: 64 cp2 x N x 2 bf16]

#define HDIM 128

typedef __attribute__((ext_vector_type(8))) short s8v;
typedef __attribute__((ext_vector_type(4))) float f4v;

__device__ __forceinline__ ushort f2bf(float f) {
    uint u = __float_as_uint(f);
    u += 0x7FFFu + ((u >> 16) & 1u);      // round-to-nearest-even
    return (ushort)(u >> 16);
}
__device__ __forceinline__ float bf2f(ushort h) {
    return __uint_as_float(((uint)h) << 16);
}
__device__ __forceinline__ float bflo(uint u) {
    return __uint_as_float(u << 16);
}
__device__ __forceinline__ float bfhi(uint u) {
    return __uint_as_float(u & 0xFFFF0000u);
}

// ---- CSR build with 4-way-split counters -----------------------------------

__global__ __launch_bounds__(256) void k_count(const int* __restrict__ dst,
                                               int* __restrict__ off4, int E4) {
    int t = blockIdx.x * 256 + threadIdx.x;
    if (t >= E4) return;
    int4 d = ((const int4*)dst)[t];
    atomicAdd(&off4[d.x * 4 + 0], 1);
    atomicAdd(&off4[d.y * 4 + 1], 1);
    atomicAdd(&off4[d.z * 4 + 2], 1);
    atomicAdd(&off4[d.w * 4 + 3], 1);
}

// Block-local exclusive scan of off4 (4N elems, in place) + dis = rsqrt(deg+1).
// Thread's int4 = one node's 4 sub-counts.
__global__ __launch_bounds__(256) void k_scan_blk(int* __restrict__ off4,
                                                  float* __restrict__ dis,
                                                  int* __restrict__ bsum, int N) {
    int t = threadIdx.x;
    int total = N * 4;
    int base = blockIdx.x * 1024 + t * 4;
    int4 d = make_int4(0, 0, 0, 0);
    if (base < total) {
        d = *(const int4*)(off4 + base);
        dis[base >> 2] = rsqrtf((float)(d.x + d.y + d.z + d.w + 1));
    }
    int tsum = d.x + d.y + d.z + d.w;
    int lane = t & 63;
    int incl = tsum;
    #pragma unroll
    for (int ofs = 1; ofs < 64; ofs <<= 1) {
        int u = __shfl_up(incl, ofs);
        if (lane >= ofs) incl += u;
    }
    __shared__ int wsum[4];
    if (lane == 63) wsum[t >> 6] = incl;
    __syncthreads();
    int w = t >> 6;
    int woff = 0;
    for (int i = 0; i < w; ++i) woff += wsum[i];

    int run = woff + incl - tsum;  // exclusive prefix (block-local)
    if (base < total) {
        off4[base + 0] = run; run += d.x;
        off4[base + 1] = run; run += d.y;
        off4[base + 2] = run; run += d.z;
        off4[base + 3] = run;
    }
    if (t == 255) bsum[blockIdx.x] = woff + incl;  // block total
}

__global__ __launch_bounds__(256) void k_scan_add(int* __restrict__ off4,
                                                  const int* __restrict__ bsum, int N) {
    int bid = blockIdx.x;
    if (bid == 0) return;
    int p = 0;
    for (int i = 0; i < bid; ++i) p += bsum[i];
    int base = bid * 1024 + threadIdx.x * 4;
    if (base < N * 4) {
        int4 v = *(const int4*)(off4 + base);
        v.x += p; v.y += p; v.z += p; v.w += p;
        *(int4*)(off4 + base) = v;
    }
}

// fill: pos = off4[dst*4+r]++ ; csr[pos] = src. Post-fill off4[j] = incl end
// of sub-segment j; node v's edges span [off4[4v-1], off4[4v+3]].
__global__ __launch_bounds__(256) void k_fill(const int* __restrict__ src,
                                              const int* __restrict__ dst,
                                              int* __restrict__ off4,
                                              int* __restrict__ csr, int E4) {
    int t = blockIdx.x * 256 + threadIdx.x;
    if (t >= E4) return;
    int4 s = ((const int4*)src)[t];
    int4 d = ((const int4*)dst)[t];
    int p0 = atomicAdd(&off4[d.x * 4 + 0], 1); csr[p0] = s.x;
    int p1 = atomicAdd(&off4[d.y * 4 + 1], 1); csr[p1] = s.y;
    int p2 = atomicAdd(&off4[d.z * 4 + 2], 1); csr[p2] = s.z;
    int p3 = atomicAdd(&off4[d.w * 4 + 3], 1); csr[p3] = s.w;
}

// ---- preprocessing ---------------------------------------------------------
// [0,nbZ) zero off4; [nbZ,nbZ+256) wconv; rest xconv (row-major hi/lo split).
__global__ __launch_bounds__(256) void k_pre(const float* __restrict__ W_in,
                                             const float* __restrict__ Ws,
                                             ushort* __restrict__ Wf,
                                             const float* __restrict__ x,
                                             ushort* __restrict__ hh,
                                             ushort* __restrict__ hl,
                                             int* __restrict__ off4,
                                             int N, int nbZ, int total4) {
    int bid = blockIdx.x;
    if (bid < nbZ) {
        int i = bid * 256 + threadIdx.x;
        if (i < N * 4) off4[i] = 0;
    } else if (bid < nbZ + 256) {
        int idx = (bid - nbZ) * 256 + threadIdx.x;   // 4 * 16384
        int m = idx >> 14;
        int e = idx & 16383;
        int k = e >> 7, col = e & 127;
        const float* srcm = (m == 0) ? W_in : (Ws + (m - 1) * 16384);
        float w = srcm[k * 128 + col];
        ushort hi = f2bf(w);
        ushort lo = f2bf(w - bf2f(hi));
        int ks = k >> 5, lk = (k >> 3) & 3, j = k & 7;
        int ct = col >> 4, lane = lk * 16 + (col & 15);
        int o = m * 32768 + (ks * 8 + ct) * 512 + lane * 8 + j;
        Wf[o] = hi;
        Wf[o + 16384] = lo;
    } else {
        int i = (bid - nbZ - 256) * 256 + threadIdx.x;
        if (i >= total4) return;
        float4 v = ((const float4*)x)[i];
        ushort a0 = f2bf(v.x), a1 = f2bf(v.y), a2 = f2bf(v.z), a3 = f2bf(v.w);
        uint2 ph, pl;
        ph.x = (uint)a0 | ((uint)a1 << 16);
        ph.y = (uint)a2 | ((uint)a3 << 16);
        pl.x = (uint)f2bf(v.x - bf2f(a0)) | ((uint)f2bf(v.y - bf2f(a1)) << 16);
        pl.y = (uint)f2bf(v.z - bf2f(a2)) | ((uint)f2bf(v.w - bf2f(a3)) << 16);
        ((uint2*)hh)[i] = ph;
        ((uint2*)hl)[i] = pl;
    }
}

// ---- MFMA GEMM -------------------------------------------------------------
// out[M,128] = (Ahi+Alo)[M,128] @ W[128,128], 3-term bf16 split.
// Wave = 16 rows x 64 cols (strip = gw>>1, col-half = gw&1) -> 2500 waves.
// MODE 1: write hi/lo split pair ROW-major (+bias) -> next mgemm's A.
// MODE 0: write bf16 into colpair-major xwb [cp2=col/2][row][col%2] (x scale).
template<int MODE>
__global__ __launch_bounds__(256) void k_mgemm(const ushort* Ahi, const ushort* Alo,
                                               const ushort* __restrict__ Wf,
                                               const float* __restrict__ bias,
                                               const float* __restrict__ scale,
                                               ushort* xwb, ushort* outhi,
                                               ushort* outlo, int M) {
    int l = threadIdx.x & 63;
    int gw = blockIdx.x * 4 + (threadIdx.x >> 6);
    int strip = gw >> 1, ch = gw & 1;
    int r0 = strip * 16;
    int lr = l & 15, lk = l >> 4;
    int ar = r0 + lr; if (ar >= M) ar = M - 1;

    // preload ALL A fragments for this wave (8 x 16B)
    s8v ah0 = *(const s8v*)(Ahi + (long long)ar * HDIM + lk * 8);
    s8v ah1 = *(const s8v*)(Ahi + (long long)ar * HDIM + lk * 8 + 32);
    s8v ah2 = *(const s8v*)(Ahi + (long long)ar * HDIM + lk * 8 + 64);
    s8v ah3 = *(const s8v*)(Ahi + (long long)ar * HDIM + lk * 8 + 96);
    s8v al0 = *(const s8v*)(Alo + (long long)ar * HDIM + lk * 8);
    s8v al1 = *(const s8v*)(Alo + (long long)ar * HDIM + lk * 8 + 32);
    s8v al2 = *(const s8v*)(Alo + (long long)ar * HDIM + lk * 8 + 64);
    s8v al3 = *(const s8v*)(Alo + (long long)ar * HDIM + lk * 8 + 96);
    __syncthreads();   // all A reads done before any in-place write below

    f4v acc[4];
    #pragma unroll
    for (int c = 0; c < 4; ++c) acc[c] = (f4v){0.f, 0.f, 0.f, 0.f};

#define KSTEP(AH, AL, ksi)                                                          \
    {                                                                               \
        const ushort* wb = Wf + ((ksi) * 8 + ch * 4) * 512 + l * 8;                 \
        _Pragma("unroll")                                                           \
        for (int c = 0; c < 4; ++c) {                                               \
            s8v bh = *(const s8v*)(wb + c * 512);                                   \
            s8v bl = *(const s8v*)(wb + 16384 + c * 512);                           \
            acc[c] = __builtin_amdgcn_mfma_f32_16x16x32_bf16(AH, bh, acc[c], 0,0,0);\
            acc[c] = __builtin_amdgcn_mfma_f32_16x16x32_bf16(AH, bl, acc[c], 0,0,0);\
            acc[c] = __builtin_amdgcn_mfma_f32_16x16x32_bf16(AL, bh, acc[c], 0,0,0);\
        }                                                                           \
    }
    KSTEP(ah0, al0, 0)
    KSTEP(ah1, al1, 1)
    KSTEP(ah2, al2, 2)
    KSTEP(ah3, al3, 3)
#undef KSTEP

    if (r0 >= M) return;
    float bbv[4], sc[4];
    #pragma unroll
    for (int c = 0; c < 4; ++c) bbv[c] = bias ? bias[(ch * 4 + c) * 16 + lr] : 0.f;
    #pragma unroll
    for (int j = 0; j < 4; ++j) sc[j] = scale ? scale[r0 + lk * 4 + j] : 1.f;

    #pragma unroll
    for (int c = 0; c < 4; ++c) {
        #pragma unroll
        for (int j = 0; j < 4; ++j) {
            int row = r0 + lk * 4 + j;
            if (row >= M) continue;
            float o = (acc[c][j] + bbv[c]) * sc[j];
            int col = (ch * 4 + c) * 16 + lr;
            if (MODE) {
                ushort h = f2bf(o);
                outhi[(long long)row * HDIM + col] = h;
                outlo[(long long)row * HDIM + col] = f2bf(o - bf2f(h));
            } else {
                int cp2 = col >> 1, ci = col & 1;
                xwb[((long long)cp2 * M + row) * 2 + ci] = f2bf(o);
            }
        }
    }
}

// ---- LDS-staged aggregation ------------------------------------------------
// Block = 1024 thr, owns col-group g (4 cols = cp2 {2g,2g+1}) x node chunk.
// Stages its 4 cols for ALL N nodes into 160KB LDS, then 2 nodes per wave:
// lane = (half = node, q = edge slot 0..15, cpp = col-pair). csr loaded
// coalesced (32 edges per node per round), distributed via shfl; payload
// from LDS; shfl_xor(2,4,8,16) reduce over q. No L2 gathers at all.
// LAST: q==0 lanes write fp32 d_out; else bf16 hi/lo split (row-major).
template<int LAST>
__global__ __launch_bounds__(1024) void k_agg(const int* __restrict__ off4,
                                              const int* __restrict__ csr,
                                              const float* __restrict__ dis,
                                              const ushort* __restrict__ xwb,
                                              const float* __restrict__ b,
                                              float* __restrict__ outf,
                                              ushort* __restrict__ outhi,
                                              ushort* __restrict__ outlo,
                                              int N, int chunkN) {
    __shared__ uint xl4[40000];            // 160 KB: 2 slabs x N uints
    int g = blockIdx.x & 31;
    int chunk = blockIdx.x >> 5;

    {   // stage: contiguous 160000 B = 10000 float4
        const float4* s4 = (const float4*)(xwb + (long long)g * N * 4);
        float4* d4 = (float4*)xl4;
        int tot = N / 2;                   // N*8 bytes / 16
        for (int i = threadIdx.x; i < tot; i += 1024) d4[i] = s4[i];
    }
    __syncthreads();

    int lane = threadIdx.x & 63;
    int wv = threadIdx.x >> 6;
    int cpp = lane & 1;
    int q = (lane >> 1) & 15;
    int half = lane >> 5;
    int half32 = half << 5;
    int hl5 = lane & 31;

    int base = chunk * chunkN;
    int limit = min(N, base + chunkN);
    int per = (chunkN + 15) >> 4;
    int wlo = base + wv * per;
    int whiW = min(wlo + per, limit);

    float bbx = b[g * 4 + cpp * 2];
    float bby = b[g * 4 + cpp * 2 + 1];
    const uint* slab = xl4 + cpp * N;

    for (int v0 = wlo; v0 < whiW; v0 += 2) {
        int nv = v0 + half;
        bool actn = nv < whiW;
        int nvc = actn ? nv : (whiW - 1);
        int nv4 = nvc * 4;
        int stt = (nvc > 0) ? off4[nv4 - 1] : 0;
        int edn = off4[nv4 + 3];

        // self term on q==0 lanes
        uint su = slab[nvc];
        float ax = (q == 0) ? bflo(su) : 0.f;
        float ay = (q == 0) ? bfhi(su) : 0.f;

        int pos = stt;
        while (__any(pos < edn)) {
            int c = csr[pos + hl5];            // coalesced, 2 segments
            bool a0 = (pos + q) < edn;
            bool a1 = (pos + 16 + q) < edn;
            int s0 = __shfl(c, half32 + q);
            int s1 = __shfl(c, half32 + 16 + q);
            s0 = a0 ? s0 : 0;
            s1 = a1 ? s1 : 0;
            uint u0 = slab[s0];
            uint u1 = slab[s1];
            ax += a0 ? bflo(u0) : 0.f;
            ay += a0 ? bfhi(u0) : 0.f;
            ax += a1 ? bflo(u1) : 0.f;
            ay += a1 ? bfhi(u1) : 0.f;
            pos += 32;
        }

        // reduce over q (lane bits 1..4)
        ax += __shfl_xor(ax, 2);  ay += __shfl_xor(ay, 2);
        ax += __shfl_xor(ax, 4);  ay += __shfl_xor(ay, 4);
        ax += __shfl_xor(ax, 8);  ay += __shfl_xor(ay, 8);
        ax += __shfl_xor(ax, 16); ay += __shfl_xor(ay, 16);

        if (q == 0 && actn) {
            float dv = dis[nvc];
            float ox = fmaxf(fmaf(dv, ax, bbx), 0.f);
            float oy = fmaxf(fmaf(dv, ay, bby), 0.f);
            long long col0 = g * 4 + cpp * 2;
            if (LAST) {
                *(float2*)(outf + (long long)nv * HDIM + col0) = make_float2(ox, oy);
            } else {
                ushort h0 = f2bf(ox), h1 = f2bf(oy);
                *(uint*)(outhi + (long long)nv * HDIM + col0) =
                    (uint)h0 | ((uint)h1 << 16);
                *(uint*)(outlo + (long long)nv * HDIM + col0) =
                    (uint)f2bf(ox - bf2f(h0)) | ((uint)f2bf(oy - bf2f(h1)) << 16);
            }
        }
    }
}

extern "C" void kernel_launch(void* const* d_in, const int* in_sizes, int n_in,
                              void* d_out, int out_size, void* d_ws, size_t ws_size,
                              hipStream_t stream) {
    const float* x    = (const float*)d_in[0];
    const int*   ei   = (const int*)d_in[1];   // [2, E]: first E = src, next E = dst
    const float* W_in = (const float*)d_in[2];
    const float* b_in = (const float*)d_in[3];
    const float* Ws   = (const float*)d_in[4]; // [3,128,128]
    const float* bs   = (const float*)d_in[5]; // [3,128]

    const int N = in_sizes[0] / HDIM;
    const int E = in_sizes[1] / 2;
    const int* src = ei;
    const int* dst = ei + E;

    float*  dis = (float*)d_ws;                      // N floats
    int*    off4 = (int*)(dis + N);                  // 4N ints (split counters)
    int*    csr = off4 + 4 * N;                      // E ints (first ~80 = scan bsums, transient)
    ushort* hh  = (ushort*)(csr + E);                // N*128 bf16 (h hi, row-major)
    ushort* hl  = hh + (long long)N * HDIM;          // N*128 bf16 (h lo, row-major)
    ushort* xwb = hl + (long long)N * HDIM;          // [64 cp2][N][2] bf16, dis-prescaled
    ushort* Wf  = (ushort*)d_out;                    // 4*64KB scratch, overwritten by last agg

    int nbZ     = (4 * N + 255) / 256;
    int nb_E4   = (E / 4 + 255) / 256;
    int nb_scan = (4 * N + 1023) / 1024;
    int nwaves  = ((N + 15) / 16) * 2;
    int nb_mg   = (nwaves + 3) / 4;
    int total4  = N * (HDIM / 4);
    int nb_x4   = (total4 + 255) / 256;
    int nb_pre  = nbZ + 256 + nb_x4;
    int chunkN  = (N + 7) / 8;
    int nb_agg  = 32 * 8;

    // preprocessing (zero off4 + weight fragments + x split) in one dispatch
    k_pre<<<nb_pre, 256, 0, stream>>>(W_in, Ws, Wf, x, hh, hl, off4, N, nbZ, total4);

    // CSR build + dis (4-way-split counters)
    k_count   <<<nb_E4,   256, 0, stream>>>(dst, off4, E / 4);
    k_scan_blk<<<nb_scan, 256, 0, stream>>>(off4, dis, csr, N);
    k_scan_add<<<nb_scan, 256, 0, stream>>>(off4, csr, N);
    k_fill    <<<nb_E4,   256, 0, stream>>>(src, dst, off4, csr, E / 4);

    // h0 = x @ W_in + b_in   (bf16-split output, in place; synced inside)
    k_mgemm<1><<<nb_mg, 256, 0, stream>>>(hh, hl, Wf, b_in, nullptr,
                                          nullptr, hh, hl, N);

    for (int layer = 0; layer < 3; ++layer) {
        const ushort* Wfm = Wf + (long long)(layer + 1) * 32768;
        const float* b = bs + (long long)layer * HDIM;
        // xwb = bf16( (h @ W) * dis[row] ), colpair-major
        k_mgemm<0><<<nb_mg, 256, 0, stream>>>(hh, hl, Wfm, nullptr, dis,
                                              xwb, nullptr, nullptr, N);
        if (layer == 2)
            k_agg<1><<<nb_agg, 1024, 0, stream>>>(off4, csr, dis, xwb, b,
                                                  (float*)d_out, nullptr, nullptr,
                                                  N, chunkN);
        else
            k_agg<0><<<nb_agg, 1024, 0, stream>>>(off4, csr, dis, xwb, b,
                                                  nullptr, hh, hl, N, chunkN);
    }
}

// Round 13
// 169.301 us; speedup vs baseline: 2.7601x; 2.7601x over previous
//
#include <hip/hip_runtime.h>
#include <hip/hip_bf16.h>

// GCN encoder: h = relu(Agg(h @ W)) x3 after input linear.
// N=20000 nodes, E=640000 edges, H=128.
// R1->R2: CSR pull-agg replaced atomics (3330->367us).
// R2->R6: GEMM evolution (367->282us). R6->R7: MFMA bf16-split GEMM (245us).
// R8->R9: bf16 payload + 2-slice L2-resident agg (FETCH 107->20.5MB).
// R9->R10: de-LDS'd index arrays (197us). R10->R11: MLP boost (193us);
//          agg is at the L2 random-gather wall (~7TB/s over minimal 164MB).
// R11->R12: LDS-staged agg REGRESSION (467us): 32 col-groups => every block
//          walks the whole edge list = 16-32x per-edge instruction redundancy.
// R12->R13: agg reverted to R11 form. CSR build rebuilt: 4-way split
//          counters (less atomic contention) + RANK TRICK -- count's
//          atomicAdd return value is the edge's slot rank, stored to rank[];
//          fill becomes atomic-free scatter csr[off4[dst*4+r]+rank]=src.
//          off4 stays exclusive prefix; off4[4N]=E; agg reads
//          start=off4[4v], end=off4[4v+4].
// ws layout: [dis: N f][off4: 4N+4 i][csr: E i][rank: E i]
//            [hh: N*128 bf16][hl: N*128 bf16][xwb: 2 x N x 64 bf16]

#define HDIM 128

typedef __attribute__((ext_vector_type(8))) short s8v;
typedef __attribute__((ext_vector_type(4))) float f4v;

__device__ __forceinline__ ushort f2bf(float f) {
    uint u = __float_as_uint(f);
    u += 0x7FFFu + ((u >> 16) & 1u);      // round-to-nearest-even
    return (ushort)(u >> 16);
}
__device__ __forceinline__ float bf2f(ushort h) {
    return __uint_as_float(((uint)h) << 16);
}

// ---- CSR build: 4-way-split counters + rank trick --------------------------

// count + rank: rank[e] = old value of off4[dst*4 + (e&3)]
__global__ __launch_bounds__(256) void k_count(const int* __restrict__ dst,
                                               int* __restrict__ off4,
                                               int* __restrict__ rank, int E4) {
    int t = blockIdx.x * 256 + threadIdx.x;
    if (t >= E4) return;
    int4 d = ((const int4*)dst)[t];
    int4 r;
    r.x = atomicAdd(&off4[d.x * 4 + 0], 1);
    r.y = atomicAdd(&off4[d.y * 4 + 1], 1);
    r.z = atomicAdd(&off4[d.z * 4 + 2], 1);
    r.w = atomicAdd(&off4[d.w * 4 + 3], 1);
    ((int4*)rank)[t] = r;
}

// Block-local exclusive scan of off4 (4N elems, in place) + dis = rsqrt(deg+1).
__global__ __launch_bounds__(256) void k_scan_blk(int* __restrict__ off4,
                                                  float* __restrict__ dis,
                                                  int* __restrict__ bsum, int N) {
    int t = threadIdx.x;
    int total = N * 4;
    int base = blockIdx.x * 1024 + t * 4;
    int4 d = make_int4(0, 0, 0, 0);
    if (base < total) {
        d = *(const int4*)(off4 + base);
        dis[base >> 2] = rsqrtf((float)(d.x + d.y + d.z + d.w + 1));
    }
    int tsum = d.x + d.y + d.z + d.w;
    int lane = t & 63;
    int incl = tsum;
    #pragma unroll
    for (int ofs = 1; ofs < 64; ofs <<= 1) {
        int u = __shfl_up(incl, ofs);
        if (lane >= ofs) incl += u;
    }
    __shared__ int wsum[4];
    if (lane == 63) wsum[t >> 6] = incl;
    __syncthreads();
    int w = t >> 6;
    int woff = 0;
    for (int i = 0; i < w; ++i) woff += wsum[i];

    int run = woff + incl - tsum;  // exclusive prefix (block-local)
    if (base < total) {
        off4[base + 0] = run; run += d.x;
        off4[base + 1] = run; run += d.y;
        off4[base + 2] = run; run += d.z;
        off4[base + 3] = run;
    }
    if (t == 255) bsum[blockIdx.x] = woff + incl;  // block total
}

__global__ __launch_bounds__(256) void k_scan_add(int* __restrict__ off4,
                                                  const int* __restrict__ bsum,
                                                  int N, int E) {
    int bid = blockIdx.x;
    if (bid == 0) {
        if (threadIdx.x == 0) off4[N * 4] = E;   // sentinel: end of last node
        return;
    }
    int p = 0;
    for (int i = 0; i < bid; ++i) p += bsum[i];
    int base = bid * 1024 + threadIdx.x * 4;
    if (base < N * 4) {
        int4 v = *(const int4*)(off4 + base);
        v.x += p; v.y += p; v.z += p; v.w += p;
        *(int4*)(off4 + base) = v;
    }
}

// atomic-free fill: csr[off4[dst*4+r] + rank] = src
__global__ __launch_bounds__(256) void k_fill(const int* __restrict__ src,
                                              const int* __restrict__ dst,
                                              const int* __restrict__ off4,
                                              const int* __restrict__ rank,
                                              int* __restrict__ csr, int E4) {
    int t = blockIdx.x * 256 + threadIdx.x;
    if (t >= E4) return;
    int4 s = ((const int4*)src)[t];
    int4 d = ((const int4*)dst)[t];
    int4 r = ((const int4*)rank)[t];
    csr[off4[d.x * 4 + 0] + r.x] = s.x;
    csr[off4[d.y * 4 + 1] + r.y] = s.y;
    csr[off4[d.z * 4 + 2] + r.z] = s.z;
    csr[off4[d.w * 4 + 3] + r.w] = s.w;
}

// ---- preprocessing ---------------------------------------------------------
// [0,nbZ) zero off4; [nbZ,nbZ+256) wconv; rest xconv.
__global__ __launch_bounds__(256) void k_pre(const float* __restrict__ W_in,
                                             const float* __restrict__ Ws,
                                             ushort* __restrict__ Wf,
                                             const float* __restrict__ x,
                                             ushort* __restrict__ hh,
                                             ushort* __restrict__ hl,
                                             int* __restrict__ off4,
                                             int N, int nbZ, int total4) {
    int bid = blockIdx.x;
    if (bid < nbZ) {
        int i = bid * 256 + threadIdx.x;
        if (i < N * 4) off4[i] = 0;
    } else if (bid < nbZ + 256) {
        int idx = (bid - nbZ) * 256 + threadIdx.x;   // 4 * 16384
        int m = idx >> 14;
        int e = idx & 16383;
        int k = e >> 7, col = e & 127;
        const float* srcm = (m == 0) ? W_in : (Ws + (m - 1) * 16384);
        float w = srcm[k * 128 + col];
        ushort hi = f2bf(w);
        ushort lo = f2bf(w - bf2f(hi));
        int ks = k >> 5, lk = (k >> 3) & 3, j = k & 7;
        int ct = col >> 4, lane = lk * 16 + (col & 15);
        int o = m * 32768 + (ks * 8 + ct) * 512 + lane * 8 + j;
        Wf[o] = hi;
        Wf[o + 16384] = lo;
    } else {
        int i = (bid - nbZ - 256) * 256 + threadIdx.x;
        if (i >= total4) return;
        float4 v = ((const float4*)x)[i];
        ushort a0 = f2bf(v.x), a1 = f2bf(v.y), a2 = f2bf(v.z), a3 = f2bf(v.w);
        uint2 ph, pl;
        ph.x = (uint)a0 | ((uint)a1 << 16);
        ph.y = (uint)a2 | ((uint)a3 << 16);
        pl.x = (uint)f2bf(v.x - bf2f(a0)) | ((uint)f2bf(v.y - bf2f(a1)) << 16);
        pl.y = (uint)f2bf(v.z - bf2f(a2)) | ((uint)f2bf(v.w - bf2f(a3)) << 16);
        ((uint2*)hh)[i] = ph;
        ((uint2*)hl)[i] = pl;
    }
}

// ---- MFMA GEMM -------------------------------------------------------------
// out[M,128] = (Ahi+Alo)[M,128] @ W[128,128], 3-term bf16 split.
// Wave = 16 rows x 64 cols (strip = gw>>1, col-half = gw&1) -> 2500 waves.
// MODE 1: write hi/lo split pair row-major (+bias).
// MODE 0: write bf16 into SLICED xwb [slice=col/64][row][col%64] (x scale).
template<int MODE>
__global__ __launch_bounds__(256) void k_mgemm(const ushort* Ahi, const ushort* Alo,
                                               const ushort* __restrict__ Wf,
                                               const float* __restrict__ bias,
                                               const float* __restrict__ scale,
                                               ushort* xwb, ushort* outhi,
                                               ushort* outlo, int M) {
    int l = threadIdx.x & 63;
    int gw = blockIdx.x * 4 + (threadIdx.x >> 6);
    int strip = gw >> 1, ch = gw & 1;
    int r0 = strip * 16;
    int lr = l & 15, lk = l >> 4;
    int ar = r0 + lr; if (ar >= M) ar = M - 1;

    // preload ALL A fragments for this wave (8 x 16B)
    s8v ah0 = *(const s8v*)(Ahi + (long long)ar * HDIM + lk * 8);
    s8v ah1 = *(const s8v*)(Ahi + (long long)ar * HDIM + lk * 8 + 32);
    s8v ah2 = *(const s8v*)(Ahi + (long long)ar * HDIM + lk * 8 + 64);
    s8v ah3 = *(const s8v*)(Ahi + (long long)ar * HDIM + lk * 8 + 96);
    s8v al0 = *(const s8v*)(Alo + (long long)ar * HDIM + lk * 8);
    s8v al1 = *(const s8v*)(Alo + (long long)ar * HDIM + lk * 8 + 32);
    s8v al2 = *(const s8v*)(Alo + (long long)ar * HDIM + lk * 8 + 64);
    s8v al3 = *(const s8v*)(Alo + (long long)ar * HDIM + lk * 8 + 96);
    __syncthreads();   // all A reads done before any in-place write below

    f4v acc[4];
    #pragma unroll
    for (int c = 0; c < 4; ++c) acc[c] = (f4v){0.f, 0.f, 0.f, 0.f};

#define KSTEP(AH, AL, ksi)                                                          \
    {                                                                               \
        const ushort* wb = Wf + ((ksi) * 8 + ch * 4) * 512 + l * 8;                 \
        _Pragma("unroll")                                                           \
        for (int c = 0; c < 4; ++c) {                                               \
            s8v bh = *(const s8v*)(wb + c * 512);                                   \
            s8v bl = *(const s8v*)(wb + 16384 + c * 512);                           \
            acc[c] = __builtin_amdgcn_mfma_f32_16x16x32_bf16(AH, bh, acc[c], 0,0,0);\
            acc[c] = __builtin_amdgcn_mfma_f32_16x16x32_bf16(AH, bl, acc[c], 0,0,0);\
            acc[c] = __builtin_amdgcn_mfma_f32_16x16x32_bf16(AL, bh, acc[c], 0,0,0);\
        }                                                                           \
    }
    KSTEP(ah0, al0, 0)
    KSTEP(ah1, al1, 1)
    KSTEP(ah2, al2, 2)
    KSTEP(ah3, al3, 3)
#undef KSTEP

    if (r0 >= M) return;
    float bbv[4], sc[4];
    #pragma unroll
    for (int c = 0; c < 4; ++c) bbv[c] = bias ? bias[(ch * 4 + c) * 16 + lr] : 0.f;
    #pragma unroll
    for (int j = 0; j < 4; ++j) sc[j] = scale ? scale[r0 + lk * 4 + j] : 1.f;

    #pragma unroll
    for (int c = 0; c < 4; ++c) {
        #pragma unroll
        for (int j = 0; j < 4; ++j) {
            int row = r0 + lk * 4 + j;
            if (row >= M) continue;
            float o = (acc[c][j] + bbv[c]) * sc[j];
            if (MODE) {
                int col = (ch * 4 + c) * 16 + lr;
                ushort h = f2bf(o);
                outhi[(long long)row * HDIM + col] = h;
                outlo[(long long)row * HDIM + col] = f2bf(o - bf2f(h));
            } else {
                int cc = c * 16 + lr;   // col within 64-col slice ch
                xwb[((long long)ch * M + row) * 64 + cc] = f2bf(o);
            }
        }
    }
}

// ---- aggregation (R11 form; L2-sliced) -------------------------------------
// xwb [sl][row][64], 2.5MB/slice; slice = blockIdx&1 -> XCD-L2-resident.
// Quarter-wave edges: lane = (q = lane>>4 edge slot, t = lane&15 col group);
// uint2 (8B) payload loads; 32-edge unroll; named int4 scalars (rule #20);
// shfl_xor(16,32) reduce; coalesced float4/uint2 epilogue.
// start = off4[4v], end = off4[4v+4] (exclusive prefix; off4[4N]=E).
// LAST: write fp32 d_out; else bf16 hi/lo split pair (row-major).
template<int LAST>
__global__ __launch_bounds__(256) void k_agg(const int* __restrict__ off4,
                                             const int* __restrict__ csr,
                                             const float* __restrict__ dis,
                                             const ushort* __restrict__ xwb,
                                             const float* __restrict__ b,
                                             float* __restrict__ outf,
                                             ushort* __restrict__ outhi,
                                             ushort* __restrict__ outlo, int N) {
    int lane = threadIdx.x & 63;
    int wv = threadIdx.x >> 6;
    int t = lane & 15, q = lane >> 4;
    int sl = blockIdx.x & 1;
    const ushort* xs = xwb + (long long)sl * N * 64;
    int v0 = (blockIdx.x >> 1) * 4 + wv;
    int vstride = (gridDim.x >> 1) * 4;

    float4 bb = ((const float4*)(b + sl * 64))[t];   // cols 4t..4t+3

#define GATH(sidx)                                                          \
    {                                                                       \
        uint2 u = *(const uint2*)(xs + (long long)(sidx) * 64 + (t << 2));  \
        ax += bf2f((ushort)u.x); ay += bf2f((ushort)(u.x >> 16));           \
        az += bf2f((ushort)u.y); aw += bf2f((ushort)(u.y >> 16));           \
    }
#define SEL(c) (q == 0 ? (c).x : q == 1 ? (c).y : q == 2 ? (c).z : (c).w)

    for (int v = v0; v < N; v += vstride) {
        int start = off4[v << 2];
        int end   = off4[(v << 2) + 4];
        float dv = dis[v];

        float ax = 0.f, ay = 0.f, az = 0.f, aw = 0.f;
        if (q == 0) GATH(v);                         // self term

        int i = start;
        for (; i + 32 <= end; i += 32) {
            int ib = __builtin_amdgcn_readfirstlane(i);
            int4 c0 = *(const int4*)(csr + ib);
            int4 c1 = *(const int4*)(csr + ib + 4);
            int4 c2 = *(const int4*)(csr + ib + 8);
            int4 c3 = *(const int4*)(csr + ib + 12);
            int4 c4 = *(const int4*)(csr + ib + 16);
            int4 c5 = *(const int4*)(csr + ib + 20);
            int4 c6 = *(const int4*)(csr + ib + 24);
            int4 c7 = *(const int4*)(csr + ib + 28);
            int s0 = SEL(c0), s1 = SEL(c1), s2 = SEL(c2), s3 = SEL(c3);
            int s4 = SEL(c4), s5 = SEL(c5), s6 = SEL(c6), s7 = SEL(c7);
            GATH(s0); GATH(s1); GATH(s2); GATH(s3);
            GATH(s4); GATH(s5); GATH(s6); GATH(s7);
        }
        if (i + 16 <= end) {
            int ib = __builtin_amdgcn_readfirstlane(i);
            int4 c0 = *(const int4*)(csr + ib);
            int4 c1 = *(const int4*)(csr + ib + 4);
            int4 c2 = *(const int4*)(csr + ib + 8);
            int4 c3 = *(const int4*)(csr + ib + 12);
            int s0 = SEL(c0), s1 = SEL(c1), s2 = SEL(c2), s3 = SEL(c3);
            GATH(s0); GATH(s1); GATH(s2); GATH(s3);
            i += 16;
        }
        if (i + 8 <= end) {
            int ib = __builtin_amdgcn_readfirstlane(i);
            int4 c0 = *(const int4*)(csr + ib);
            int4 c1 = *(const int4*)(csr + ib + 4);
            int s0 = SEL(c0), s1 = SEL(c1);
            GATH(s0); GATH(s1);
            i += 8;
        }
        if (i + 4 <= end) {
            int ib = __builtin_amdgcn_readfirstlane(i);
            int4 c0 = *(const int4*)(csr + ib);
            int s0 = SEL(c0);
            GATH(s0);
            i += 4;
        }
        {   // remainder 0..3 edges: one predicated round
            int r = end - i;
            if (q < r) {
                int s = csr[__builtin_amdgcn_readfirstlane(i) + q];
                GATH(s);
            }
        }

        ax += __shfl_xor(ax, 16); ax += __shfl_xor(ax, 32);
        ay += __shfl_xor(ay, 16); ay += __shfl_xor(ay, 32);
        az += __shfl_xor(az, 16); az += __shfl_xor(az, 32);
        aw += __shfl_xor(aw, 16); aw += __shfl_xor(aw, 32);

        if (q == 0) {
            float ox = fmaxf(fmaf(dv, ax, bb.x), 0.f);
            float oy = fmaxf(fmaf(dv, ay, bb.y), 0.f);
            float oz = fmaxf(fmaf(dv, az, bb.z), 0.f);
            float ow = fmaxf(fmaf(dv, aw, bb.w), 0.f);
            long long oidx = (long long)v * HDIM + sl * 64 + (t << 2);
            if (LAST) {
                *(float4*)(outf + oidx) = make_float4(ox, oy, oz, ow);
            } else {
                ushort h0 = f2bf(ox), h1 = f2bf(oy), h2 = f2bf(oz), h3 = f2bf(ow);
                uint2 ph, pl;
                ph.x = (uint)h0 | ((uint)h1 << 16);
                ph.y = (uint)h2 | ((uint)h3 << 16);
                pl.x = (uint)f2bf(ox - bf2f(h0)) | ((uint)f2bf(oy - bf2f(h1)) << 16);
                pl.y = (uint)f2bf(oz - bf2f(h2)) | ((uint)f2bf(ow - bf2f(h3)) << 16);
                *(uint2*)(outhi + oidx) = ph;
                *(uint2*)(outlo + oidx) = pl;
            }
        }
    }
#undef GATH
#undef SEL
}

extern "C" void kernel_launch(void* const* d_in, const int* in_sizes, int n_in,
                              void* d_out, int out_size, void* d_ws, size_t ws_size,
                              hipStream_t stream) {
    const float* x    = (const float*)d_in[0];
    const int*   ei   = (const int*)d_in[1];   // [2, E]: first E = src, next E = dst
    const float* W_in = (const float*)d_in[2];
    const float* b_in = (const float*)d_in[3];
    const float* Ws   = (const float*)d_in[4]; // [3,128,128]
    const float* bs   = (const float*)d_in[5]; // [3,128]

    const int N = in_sizes[0] / HDIM;
    const int E = in_sizes[1] / 2;
    const int* src = ei;
    const int* dst = ei + E;

    float*  dis  = (float*)d_ws;                     // N floats
    int*    off4 = (int*)(dis + N);                  // 4N+4 ints (split counters / excl prefix)
    int*    csr  = off4 + 4 * N + 4;                 // E ints (first ~80 = scan bsums, transient)
    int*    rank = csr + E;                          // E ints
    ushort* hh   = (ushort*)(rank + E);              // N*128 bf16 (h hi, row-major)
    ushort* hl   = hh + (long long)N * HDIM;         // N*128 bf16 (h lo, row-major)
    ushort* xwb  = hl + (long long)N * HDIM;         // [2][N][64] bf16, dis-prescaled
    ushort* Wf   = (ushort*)d_out;                   // 4*64KB scratch, overwritten by last agg

    int nbZ     = (4 * N + 255) / 256;
    int nb_E4   = (E / 4 + 255) / 256;
    int nb_scan = (4 * N + 1023) / 1024;
    int nwaves  = ((N + 15) / 16) * 2;
    int nb_mg   = (nwaves + 3) / 4;
    int total4  = N * (HDIM / 4);
    int nb_x4   = (total4 + 255) / 256;
    int nb_pre  = nbZ + 256 + nb_x4;
    int nb_agg  = 2048;

    // preprocessing (zero off4 + weight fragments + x split) in one dispatch
    k_pre<<<nb_pre, 256, 0, stream>>>(W_in, Ws, Wf, x, hh, hl, off4, N, nbZ, total4);

    // CSR build + dis: count(+rank) -> scan -> atomic-free fill
    k_count   <<<nb_E4,   256, 0, stream>>>(dst, off4, rank, E / 4);
    k_scan_blk<<<nb_scan, 256, 0, stream>>>(off4, dis, csr, N);
    k_scan_add<<<nb_scan, 256, 0, stream>>>(off4, csr, N, E);
    k_fill    <<<nb_E4,   256, 0, stream>>>(src, dst, off4, rank, csr, E / 4);

    // h0 = x @ W_in + b_in   (bf16-split output, in place; synced inside)
    k_mgemm<1><<<nb_mg, 256, 0, stream>>>(hh, hl, Wf, b_in, nullptr,
                                          nullptr, hh, hl, N);

    for (int layer = 0; layer < 3; ++layer) {
        const ushort* Wfm = Wf + (long long)(layer + 1) * 32768;
        const float* b = bs + (long long)layer * HDIM;
        // xwb = bf16( (h @ W) * dis[row] ), sliced layout
        k_mgemm<0><<<nb_mg, 256, 0, stream>>>(hh, hl, Wfm, nullptr, dis,
                                              xwb, nullptr, nullptr, N);
        if (layer == 2)
            k_agg<1><<<nb_agg, 256, 0, stream>>>(off4, csr, dis, xwb, b,
                                                 (float*)d_out, nullptr, nullptr, N);
        else
            k_agg<0><<<nb_agg, 256, 0, stream>>>(off4, csr, dis, xwb, b,
                                                 nullptr, hh, hl, N);
    }
}

// Round 14
// 160.357 us; speedup vs baseline: 2.9141x; 1.0558x over previous
//
#include <hip/hip_runtime.h>
#include <hip/hip_bf16.h>

// GCN encoder: h = relu(Agg(h @ W)) x3 after input linear.
// N=20000 nodes, E=640000 edges, H=128.
// R1->R2: CSR pull-agg replaced atomics (3330->367us).
// R2->R6: GEMM evolution (367->282us). R6->R7: MFMA bf16-split GEMM (245us).
// R8->R10: bf16 payload + 2-slice L2-resident agg, no LDS spills (197us).
// R11: MLP boost (193us). R12: LDS-staged agg regression (467us; 32x edge
//      redundancy). R13: rank-trick atomic-free fill + 4-way split count (169us).
// R13->R14: (1) agg L2 warm-up: each block streams its XCD's share of the
//      slice linearly first (asm-kept-alive), converting cross-XCD dirty-line
//      first-touches (FETCH 20.5MB >> 8MB unique) from random-gather-rate to
//      streaming-rate; (2) mgemm col-half = blockIdx&1 so writer XCD parity
//      matches agg slice parity; (3) input linear folded into layer 0:
//      Wc = W_in@Ws0, bc = b_in@Ws0 computed in k_pre (no relu between ->
//      mathematically exact) -> mgemm<1> pass deleted.
// ws layout: [dis: N f][off4: 4N+4 i][csr: E i][rank: E i]
//            [hh: N*128 bf16][hl: N*128 bf16][xwb: 2 x N x 64 bf16][bc: 128 f]

#define HDIM 128

typedef __attribute__((ext_vector_type(8))) short s8v;
typedef __attribute__((ext_vector_type(4))) float f4v;

__device__ __forceinline__ ushort f2bf(float f) {
    uint u = __float_as_uint(f);
    u += 0x7FFFu + ((u >> 16) & 1u);      // round-to-nearest-even
    return (ushort)(u >> 16);
}
__device__ __forceinline__ float bf2f(ushort h) {
    return __uint_as_float(((uint)h) << 16);
}

// ---- CSR build: 4-way-split counters + rank trick --------------------------

__global__ __launch_bounds__(256) void k_count(const int* __restrict__ dst,
                                               int* __restrict__ off4,
                                               int* __restrict__ rank, int E4) {
    int t = blockIdx.x * 256 + threadIdx.x;
    if (t >= E4) return;
    int4 d = ((const int4*)dst)[t];
    int4 r;
    r.x = atomicAdd(&off4[d.x * 4 + 0], 1);
    r.y = atomicAdd(&off4[d.y * 4 + 1], 1);
    r.z = atomicAdd(&off4[d.z * 4 + 2], 1);
    r.w = atomicAdd(&off4[d.w * 4 + 3], 1);
    ((int4*)rank)[t] = r;
}

__global__ __launch_bounds__(256) void k_scan_blk(int* __restrict__ off4,
                                                  float* __restrict__ dis,
                                                  int* __restrict__ bsum, int N) {
    int t = threadIdx.x;
    int total = N * 4;
    int base = blockIdx.x * 1024 + t * 4;
    int4 d = make_int4(0, 0, 0, 0);
    if (base < total) {
        d = *(const int4*)(off4 + base);
        dis[base >> 2] = rsqrtf((float)(d.x + d.y + d.z + d.w + 1));
    }
    int tsum = d.x + d.y + d.z + d.w;
    int lane = t & 63;
    int incl = tsum;
    #pragma unroll
    for (int ofs = 1; ofs < 64; ofs <<= 1) {
        int u = __shfl_up(incl, ofs);
        if (lane >= ofs) incl += u;
    }
    __shared__ int wsum[4];
    if (lane == 63) wsum[t >> 6] = incl;
    __syncthreads();
    int w = t >> 6;
    int woff = 0;
    for (int i = 0; i < w; ++i) woff += wsum[i];

    int run = woff + incl - tsum;  // exclusive prefix (block-local)
    if (base < total) {
        off4[base + 0] = run; run += d.x;
        off4[base + 1] = run; run += d.y;
        off4[base + 2] = run; run += d.z;
        off4[base + 3] = run;
    }
    if (t == 255) bsum[blockIdx.x] = woff + incl;  // block total
}

__global__ __launch_bounds__(256) void k_scan_add(int* __restrict__ off4,
                                                  const int* __restrict__ bsum,
                                                  int N, int E) {
    int bid = blockIdx.x;
    if (bid == 0) {
        if (threadIdx.x == 0) off4[N * 4] = E;   // sentinel: end of last node
        return;
    }
    int p = 0;
    for (int i = 0; i < bid; ++i) p += bsum[i];
    int base = bid * 1024 + threadIdx.x * 4;
    if (base < N * 4) {
        int4 v = *(const int4*)(off4 + base);
        v.x += p; v.y += p; v.z += p; v.w += p;
        *(int4*)(off4 + base) = v;
    }
}

// atomic-free fill: csr[off4[dst*4+r] + rank] = src
__global__ __launch_bounds__(256) void k_fill(const int* __restrict__ src,
                                              const int* __restrict__ dst,
                                              const int* __restrict__ off4,
                                              const int* __restrict__ rank,
                                              int* __restrict__ csr, int E4) {
    int t = blockIdx.x * 256 + threadIdx.x;
    if (t >= E4) return;
    int4 s = ((const int4*)src)[t];
    int4 d = ((const int4*)dst)[t];
    int4 r = ((const int4*)rank)[t];
    csr[off4[d.x * 4 + 0] + r.x] = s.x;
    csr[off4[d.y * 4 + 1] + r.y] = s.y;
    csr[off4[d.z * 4 + 2] + r.z] = s.z;
    csr[off4[d.w * 4 + 3] + r.w] = s.w;
}

// ---- preprocessing ---------------------------------------------------------
// [0,nbZ): zero off4 | [nbZ,nbZ+192): wconv 3 matrices (m=0 computes
// Wc=W_in@Ws0 on the fly) | [nbZ+192]: bc = b_in@Ws0 | rest: xconv.
__global__ __launch_bounds__(256) void k_pre(const float* __restrict__ W_in,
                                             const float* __restrict__ Ws,
                                             const float* __restrict__ b_in,
                                             ushort* __restrict__ Wf,
                                             float* __restrict__ bc,
                                             const float* __restrict__ x,
                                             ushort* __restrict__ hh,
                                             ushort* __restrict__ hl,
                                             int* __restrict__ off4,
                                             int N, int nbZ, int total4) {
    int bid = blockIdx.x;
    if (bid < nbZ) {
        int i = bid * 256 + threadIdx.x;
        if (i < N * 4) off4[i] = 0;
    } else if (bid < nbZ + 192) {
        int idx = (bid - nbZ) * 256 + threadIdx.x;   // 3 * 16384
        int m = idx >> 14;
        int e = idx & 16383;
        int k = e >> 7, col = e & 127;
        float w;
        if (m == 0) {
            // Wc[k][col] = sum_j W_in[k][j] * Ws0[j][col]
            w = 0.f;
            #pragma unroll 8
            for (int j = 0; j < 128; ++j)
                w = fmaf(W_in[k * 128 + j], Ws[j * 128 + col], w);
        } else {
            w = Ws[m * 16384 + k * 128 + col];
        }
        ushort hi = f2bf(w);
        ushort lo = f2bf(w - bf2f(hi));
        int ks = k >> 5, lk = (k >> 3) & 3, j = k & 7;
        int ct = col >> 4, lane = lk * 16 + (col & 15);
        int o = m * 32768 + (ks * 8 + ct) * 512 + lane * 8 + j;
        Wf[o] = hi;
        Wf[o + 16384] = lo;
    } else if (bid == nbZ + 192) {
        int col = threadIdx.x;
        if (col < 128) {
            float v = 0.f;
            #pragma unroll 8
            for (int j = 0; j < 128; ++j)
                v = fmaf(b_in[j], Ws[j * 128 + col], v);
            bc[col] = v;
        }
    } else {
        int i = (bid - nbZ - 193) * 256 + threadIdx.x;
        if (i >= total4) return;
        float4 v = ((const float4*)x)[i];
        ushort a0 = f2bf(v.x), a1 = f2bf(v.y), a2 = f2bf(v.z), a3 = f2bf(v.w);
        uint2 ph, pl;
        ph.x = (uint)a0 | ((uint)a1 << 16);
        ph.y = (uint)a2 | ((uint)a3 << 16);
        pl.x = (uint)f2bf(v.x - bf2f(a0)) | ((uint)f2bf(v.y - bf2f(a1)) << 16);
        pl.y = (uint)f2bf(v.z - bf2f(a2)) | ((uint)f2bf(v.w - bf2f(a3)) << 16);
        ((uint2*)hh)[i] = ph;
        ((uint2*)hl)[i] = pl;
    }
}

// ---- MFMA GEMM -------------------------------------------------------------
// xwb[slice][M][64] = bf16(((Ahi+Alo) @ W + bias) * scale), 3-term bf16 split.
// Col-half = bid&1 (block-level -> writer XCD parity == agg slice parity);
// strip = (bid>>1)*4 + wave.
__global__ __launch_bounds__(256) void k_mgemm(const ushort* Ahi, const ushort* Alo,
                                               const ushort* __restrict__ Wf,
                                               const float* __restrict__ bias,
                                               const float* __restrict__ scale,
                                               ushort* xwb, int M) {
    int l = threadIdx.x & 63;
    int ch = blockIdx.x & 1;
    int strip = (blockIdx.x >> 1) * 4 + (threadIdx.x >> 6);
    int r0 = strip * 16;
    int lr = l & 15, lk = l >> 4;
    int ar = r0 + lr; if (ar >= M) ar = M - 1;

    // preload ALL A fragments for this wave (8 x 16B)
    s8v ah0 = *(const s8v*)(Ahi + (long long)ar * HDIM + lk * 8);
    s8v ah1 = *(const s8v*)(Ahi + (long long)ar * HDIM + lk * 8 + 32);
    s8v ah2 = *(const s8v*)(Ahi + (long long)ar * HDIM + lk * 8 + 64);
    s8v ah3 = *(const s8v*)(Ahi + (long long)ar * HDIM + lk * 8 + 96);
    s8v al0 = *(const s8v*)(Alo + (long long)ar * HDIM + lk * 8);
    s8v al1 = *(const s8v*)(Alo + (long long)ar * HDIM + lk * 8 + 32);
    s8v al2 = *(const s8v*)(Alo + (long long)ar * HDIM + lk * 8 + 64);
    s8v al3 = *(const s8v*)(Alo + (long long)ar * HDIM + lk * 8 + 96);

    f4v acc[4];
    #pragma unroll
    for (int c = 0; c < 4; ++c) acc[c] = (f4v){0.f, 0.f, 0.f, 0.f};

#define KSTEP(AH, AL, ksi)                                                          \
    {                                                                               \
        const ushort* wb = Wf + ((ksi) * 8 + ch * 4) * 512 + l * 8;                 \
        _Pragma("unroll")                                                           \
        for (int c = 0; c < 4; ++c) {                                               \
            s8v bh = *(const s8v*)(wb + c * 512);                                   \
            s8v bl = *(const s8v*)(wb + 16384 + c * 512);                           \
            acc[c] = __builtin_amdgcn_mfma_f32_16x16x32_bf16(AH, bh, acc[c], 0,0,0);\
            acc[c] = __builtin_amdgcn_mfma_f32_16x16x32_bf16(AH, bl, acc[c], 0,0,0);\
            acc[c] = __builtin_amdgcn_mfma_f32_16x16x32_bf16(AL, bh, acc[c], 0,0,0);\
        }                                                                           \
    }
    KSTEP(ah0, al0, 0)
    KSTEP(ah1, al1, 1)
    KSTEP(ah2, al2, 2)
    KSTEP(ah3, al3, 3)
#undef KSTEP

    if (r0 >= M) return;
    float bbv[4], sc[4];
    #pragma unroll
    for (int c = 0; c < 4; ++c) bbv[c] = bias ? bias[(ch * 4 + c) * 16 + lr] : 0.f;
    #pragma unroll
    for (int j = 0; j < 4; ++j) sc[j] = scale[r0 + lk * 4 + j];

    #pragma unroll
    for (int c = 0; c < 4; ++c) {
        #pragma unroll
        for (int j = 0; j < 4; ++j) {
            int row = r0 + lk * 4 + j;
            if (row >= M) continue;
            float o = (acc[c][j] + bbv[c]) * sc[j];
            int cc = c * 16 + lr;   // col within 64-col slice ch
            xwb[((long long)ch * M + row) * 64 + cc] = f2bf(o);
        }
    }
}

// ---- aggregation (L2-sliced + warm-up) -------------------------------------
// xwb [sl][row][64], 2.5MB/slice; slice = blockIdx&1 -> XCD parity.
// Warm-up: block streams its XCD-local share of the slice (linear float4)
// so cross-XCD dirty-line first-touches happen at streaming rate; gathers
// then hit local L2. Quarter-wave edges (q=edge slot, t=col group), uint2
// payload, 32-edge unroll, named int4 scalars, shfl_xor(16,32) reduce.
// LAST: write fp32 d_out; else bf16 hi/lo split pair (row-major).
template<int LAST>
__global__ __launch_bounds__(256) void k_agg(const int* __restrict__ off4,
                                             const int* __restrict__ csr,
                                             const float* __restrict__ dis,
                                             const ushort* __restrict__ xwb,
                                             const float* __restrict__ b,
                                             float* __restrict__ outf,
                                             ushort* __restrict__ outhi,
                                             ushort* __restrict__ outlo, int N) {
    int lane = threadIdx.x & 63;
    int wv = threadIdx.x >> 6;
    int t = lane & 15, q = lane >> 4;
    int sl = blockIdx.x & 1;
    const ushort* xs = xwb + (long long)sl * N * 64;

    {   // L2 warm-up: 256 blocks per XCD share one slice; each streams 1/256
        int lb = blockIdx.x >> 3;                  // XCD-local block idx 0..255
        const float4* p4 = (const float4*)xs;      // N*8 float4 per slice
        int tot = N * 8;
        int chunk = (tot + 255) >> 8;
        int lo = lb * chunk;
        int hi = lo + chunk; if (hi > tot) hi = tot;
        float acc = 0.f;
        for (int i = lo + (int)threadIdx.x; i < hi; i += 256) {
            float4 u = p4[i];
            acc += (u.x + u.y) + (u.z + u.w);
        }
        asm volatile("" :: "v"(acc));              // keep loads alive (rule #17)
    }

    int v0 = (blockIdx.x >> 1) * 4 + wv;
    int vstride = (gridDim.x >> 1) * 4;

    float4 bb = ((const float4*)(b + sl * 64))[t];   // cols 4t..4t+3

#define GATH(sidx)                                                          \
    {                                                                       \
        uint2 u = *(const uint2*)(xs + (long long)(sidx) * 64 + (t << 2));  \
        ax += bf2f((ushort)u.x); ay += bf2f((ushort)(u.x >> 16));           \
        az += bf2f((ushort)u.y); aw += bf2f((ushort)(u.y >> 16));           \
    }
#define SEL(c) (q == 0 ? (c).x : q == 1 ? (c).y : q == 2 ? (c).z : (c).w)

    for (int v = v0; v < N; v += vstride) {
        int start = off4[v << 2];
        int end   = off4[(v << 2) + 4];
        float dv = dis[v];

        float ax = 0.f, ay = 0.f, az = 0.f, aw = 0.f;
        if (q == 0) GATH(v);                         // self term

        int i = start;
        for (; i + 32 <= end; i += 32) {
            int ib = __builtin_amdgcn_readfirstlane(i);
            int4 c0 = *(const int4*)(csr + ib);
            int4 c1 = *(const int4*)(csr + ib + 4);
            int4 c2 = *(const int4*)(csr + ib + 8);
            int4 c3 = *(const int4*)(csr + ib + 12);
            int4 c4 = *(const int4*)(csr + ib + 16);
            int4 c5 = *(const int4*)(csr + ib + 20);
            int4 c6 = *(const int4*)(csr + ib + 24);
            int4 c7 = *(const int4*)(csr + ib + 28);
            int s0 = SEL(c0), s1 = SEL(c1), s2 = SEL(c2), s3 = SEL(c3);
            int s4 = SEL(c4), s5 = SEL(c5), s6 = SEL(c6), s7 = SEL(c7);
            GATH(s0); GATH(s1); GATH(s2); GATH(s3);
            GATH(s4); GATH(s5); GATH(s6); GATH(s7);
        }
        if (i + 16 <= end) {
            int ib = __builtin_amdgcn_readfirstlane(i);
            int4 c0 = *(const int4*)(csr + ib);
            int4 c1 = *(const int4*)(csr + ib + 4);
            int4 c2 = *(const int4*)(csr + ib + 8);
            int4 c3 = *(const int4*)(csr + ib + 12);
            int s0 = SEL(c0), s1 = SEL(c1), s2 = SEL(c2), s3 = SEL(c3);
            GATH(s0); GATH(s1); GATH(s2); GATH(s3);
            i += 16;
        }
        if (i + 8 <= end) {
            int ib = __builtin_amdgcn_readfirstlane(i);
            int4 c0 = *(const int4*)(csr + ib);
            int4 c1 = *(const int4*)(csr + ib + 4);
            int s0 = SEL(c0), s1 = SEL(c1);
            GATH(s0); GATH(s1);
            i += 8;
        }
        if (i + 4 <= end) {
            int ib = __builtin_amdgcn_readfirstlane(i);
            int4 c0 = *(const int4*)(csr + ib);
            int s0 = SEL(c0);
            GATH(s0);
            i += 4;
        }
        {   // remainder 0..3 edges: one predicated round
            int r = end - i;
            if (q < r) {
                int s = csr[__builtin_amdgcn_readfirstlane(i) + q];
                GATH(s);
            }
        }

        ax += __shfl_xor(ax, 16); ax += __shfl_xor(ax, 32);
        ay += __shfl_xor(ay, 16); ay += __shfl_xor(ay, 32);
        az += __shfl_xor(az, 16); az += __shfl_xor(az, 32);
        aw += __shfl_xor(aw, 16); aw += __shfl_xor(aw, 32);

        if (q == 0) {
            float ox = fmaxf(fmaf(dv, ax, bb.x), 0.f);
            float oy = fmaxf(fmaf(dv, ay, bb.y), 0.f);
            float oz = fmaxf(fmaf(dv, az, bb.z), 0.f);
            float ow = fmaxf(fmaf(dv, aw, bb.w), 0.f);
            long long oidx = (long long)v * HDIM + sl * 64 + (t << 2);
            if (LAST) {
                *(float4*)(outf + oidx) = make_float4(ox, oy, oz, ow);
            } else {
                ushort h0 = f2bf(ox), h1 = f2bf(oy), h2 = f2bf(oz), h3 = f2bf(ow);
                uint2 ph, pl;
                ph.x = (uint)h0 | ((uint)h1 << 16);
                ph.y = (uint)h2 | ((uint)h3 << 16);
                pl.x = (uint)f2bf(ox - bf2f(h0)) | ((uint)f2bf(oy - bf2f(h1)) << 16);
                pl.y = (uint)f2bf(oz - bf2f(h2)) | ((uint)f2bf(ow - bf2f(h3)) << 16);
                *(uint2*)(outhi + oidx) = ph;
                *(uint2*)(outlo + oidx) = pl;
            }
        }
    }
#undef GATH
#undef SEL
}

extern "C" void kernel_launch(void* const* d_in, const int* in_sizes, int n_in,
                              void* d_out, int out_size, void* d_ws, size_t ws_size,
                              hipStream_t stream) {
    const float* x    = (const float*)d_in[0];
    const int*   ei   = (const int*)d_in[1];   // [2, E]: first E = src, next E = dst
    const float* W_in = (const float*)d_in[2];
    const float* b_in = (const float*)d_in[3];
    const float* Ws   = (const float*)d_in[4]; // [3,128,128]
    const float* bs   = (const float*)d_in[5]; // [3,128]

    const int N = in_sizes[0] / HDIM;
    const int E = in_sizes[1] / 2;
    const int* src = ei;
    const int* dst = ei + E;

    float*  dis  = (float*)d_ws;                     // N floats
    int*    off4 = (int*)(dis + N);                  // 4N+4 ints (excl prefix)
    int*    csr  = off4 + 4 * N + 4;                 // E ints (first ~80 = scan bsums, transient)
    int*    rank = csr + E;                          // E ints
    ushort* hh   = (ushort*)(rank + E);              // N*128 bf16 (h hi, row-major)
    ushort* hl   = hh + (long long)N * HDIM;         // N*128 bf16 (h lo, row-major)
    ushort* xwb  = hl + (long long)N * HDIM;         // [2][N][64] bf16, dis-prescaled
    float*  bc   = (float*)(xwb + (long long)2 * N * 64); // 128 floats (b_in@Ws0)
    ushort* Wf   = (ushort*)d_out;                   // 3*64KB scratch, overwritten by last agg

    int nbZ     = (4 * N + 255) / 256;
    int nb_E4   = (E / 4 + 255) / 256;
    int nb_scan = (4 * N + 1023) / 1024;
    int strips  = (N + 15) / 16;
    int nb_mg   = 2 * ((strips + 3) / 4);
    int total4  = N * (HDIM / 4);
    int nb_x4   = (total4 + 255) / 256;
    int nb_pre  = nbZ + 192 + 1 + nb_x4;
    int nb_agg  = 2048;

    // preprocessing: zero off4 | Wc/W1/W2 fragments | bc | x split
    k_pre<<<nb_pre, 256, 0, stream>>>(W_in, Ws, b_in, Wf, bc, x, hh, hl,
                                      off4, N, nbZ, total4);

    // CSR build + dis: count(+rank) -> scan -> atomic-free fill
    k_count   <<<nb_E4,   256, 0, stream>>>(dst, off4, rank, E / 4);
    k_scan_blk<<<nb_scan, 256, 0, stream>>>(off4, dis, csr, N);
    k_scan_add<<<nb_scan, 256, 0, stream>>>(off4, csr, N, E);
    k_fill    <<<nb_E4,   256, 0, stream>>>(src, dst, off4, rank, csr, E / 4);

    for (int layer = 0; layer < 3; ++layer) {
        const ushort* Wfm = Wf + (long long)layer * 32768;
        const float* b = bs + (long long)layer * HDIM;
        const ushort* Ah = (layer == 0) ? hh : hh;   // layer0 reads x splits
        // layer 0: A = x splits, bias = bc (folded input linear); else A = h splits
        k_mgemm<<<nb_mg, 256, 0, stream>>>(hh, hl, Wfm,
                                           (layer == 0) ? bc : nullptr,
                                           dis, xwb, N);
        if (layer == 2)
            k_agg<1><<<nb_agg, 256, 0, stream>>>(off4, csr, dis, xwb, b,
                                                 (float*)d_out, nullptr, nullptr, N);
        else
            k_agg<0><<<nb_agg, 256, 0, stream>>>(off4, csr, dis, xwb, b,
                                                 nullptr, hh, hl, N);
        (void)Ah;
    }
}

// Round 16
// 157.857 us; speedup vs baseline: 2.9602x; 1.0158x over previous
//
#include <hip/hip_runtime.h>
#include <hip/hip_bf16.h>

// GCN encoder: h = relu(Agg(h @ W)) x3 (input linear folded into layer 0).
// N=20000 nodes, E=640000 edges, H=128.
// R1->R13: atomics->CSR pull (3330->367), MFMA bf16-split GEMM (245),
//   bf16 payload + 2-slice L2-resident agg + no LDS spills (197->193),
//   rank-trick atomic-free fill + 4-way split count (169).
// R14: agg L2 warm-up + W_in@Ws0 fold (160us).
// R15: cooperative mega-kernel FAILED to launch (silent error, zeros out;
//   grid=1024 likely exceeded computed co-residency). Reverted.
// R15->R16: layer-0 mgemm reads x (fp32) directly, splitting to bf16 hi/lo
//   in registers -> xconv phase deleted (30MB of pre traffic gone). A-read
//   bytes in mgemm unchanged (32B/lane either way).
// ws: [dis N f][off4 4N+4 i][csr E i][rank E i][hh N*128 bf16][hl N*128 bf16]
//     [xwb 2xNx64 bf16][bc 128 f]      Wf = d_out[0:192KB] scratch.

#define HDIM 128

typedef __attribute__((ext_vector_type(8))) short s8v;
typedef __attribute__((ext_vector_type(4))) float f4v;

__device__ __forceinline__ ushort f2bf(float f) {
    uint u = __float_as_uint(f);
    u += 0x7FFFu + ((u >> 16) & 1u);      // round-to-nearest-even
    return (ushort)(u >> 16);
}
__device__ __forceinline__ float bf2f(ushort h) {
    return __uint_as_float(((uint)h) << 16);
}
// split 8 consecutive fp32 into bf16 hi/lo fragments (all indices constant)
__device__ __forceinline__ void split8(float4 a, float4 b, s8v& hi, s8v& lo) {
    ushort h0 = f2bf(a.x), h1 = f2bf(a.y), h2 = f2bf(a.z), h3 = f2bf(a.w);
    ushort h4 = f2bf(b.x), h5 = f2bf(b.y), h6 = f2bf(b.z), h7 = f2bf(b.w);
    hi[0] = (short)h0; hi[1] = (short)h1; hi[2] = (short)h2; hi[3] = (short)h3;
    hi[4] = (short)h4; hi[5] = (short)h5; hi[6] = (short)h6; hi[7] = (short)h7;
    lo[0] = (short)f2bf(a.x - bf2f(h0)); lo[1] = (short)f2bf(a.y - bf2f(h1));
    lo[2] = (short)f2bf(a.z - bf2f(h2)); lo[3] = (short)f2bf(a.w - bf2f(h3));
    lo[4] = (short)f2bf(b.x - bf2f(h4)); lo[5] = (short)f2bf(b.y - bf2f(h5));
    lo[6] = (short)f2bf(b.z - bf2f(h6)); lo[7] = (short)f2bf(b.w - bf2f(h7));
}

// ---- CSR build: 4-way-split counters + rank trick --------------------------

__global__ __launch_bounds__(256) void k_count(const int* __restrict__ dst,
                                               int* __restrict__ off4,
                                               int* __restrict__ rank, int E4) {
    int t = blockIdx.x * 256 + threadIdx.x;
    if (t >= E4) return;
    int4 d = ((const int4*)dst)[t];
    int4 r;
    r.x = atomicAdd(&off4[d.x * 4 + 0], 1);
    r.y = atomicAdd(&off4[d.y * 4 + 1], 1);
    r.z = atomicAdd(&off4[d.z * 4 + 2], 1);
    r.w = atomicAdd(&off4[d.w * 4 + 3], 1);
    ((int4*)rank)[t] = r;
}

__global__ __launch_bounds__(256) void k_scan_blk(int* __restrict__ off4,
                                                  float* __restrict__ dis,
                                                  int* __restrict__ bsum, int N) {
    int t = threadIdx.x;
    int total = N * 4;
    int base = blockIdx.x * 1024 + t * 4;
    int4 d = make_int4(0, 0, 0, 0);
    if (base < total) {
        d = *(const int4*)(off4 + base);
        dis[base >> 2] = rsqrtf((float)(d.x + d.y + d.z + d.w + 1));
    }
    int tsum = d.x + d.y + d.z + d.w;
    int lane = t & 63;
    int incl = tsum;
    #pragma unroll
    for (int ofs = 1; ofs < 64; ofs <<= 1) {
        int u = __shfl_up(incl, ofs);
        if (lane >= ofs) incl += u;
    }
    __shared__ int wsum[4];
    if (lane == 63) wsum[t >> 6] = incl;
    __syncthreads();
    int w = t >> 6;
    int woff = 0;
    for (int i = 0; i < w; ++i) woff += wsum[i];

    int run = woff + incl - tsum;  // exclusive prefix (block-local)
    if (base < total) {
        off4[base + 0] = run; run += d.x;
        off4[base + 1] = run; run += d.y;
        off4[base + 2] = run; run += d.z;
        off4[base + 3] = run;
    }
    if (t == 255) bsum[blockIdx.x] = woff + incl;  // block total
}

__global__ __launch_bounds__(256) void k_scan_add(int* __restrict__ off4,
                                                  const int* __restrict__ bsum,
                                                  int N, int E) {
    int bid = blockIdx.x;
    if (bid == 0) {
        if (threadIdx.x == 0) off4[N * 4] = E;   // sentinel: end of last node
        return;
    }
    int p = 0;
    for (int i = 0; i < bid; ++i) p += bsum[i];
    int base = bid * 1024 + threadIdx.x * 4;
    if (base < N * 4) {
        int4 v = *(const int4*)(off4 + base);
        v.x += p; v.y += p; v.z += p; v.w += p;
        *(int4*)(off4 + base) = v;
    }
}

// atomic-free fill: csr[off4[dst*4+r] + rank] = src
__global__ __launch_bounds__(256) void k_fill(const int* __restrict__ src,
                                              const int* __restrict__ dst,
                                              const int* __restrict__ off4,
                                              const int* __restrict__ rank,
                                              int* __restrict__ csr, int E4) {
    int t = blockIdx.x * 256 + threadIdx.x;
    if (t >= E4) return;
    int4 s = ((const int4*)src)[t];
    int4 d = ((const int4*)dst)[t];
    int4 r = ((const int4*)rank)[t];
    csr[off4[d.x * 4 + 0] + r.x] = s.x;
    csr[off4[d.y * 4 + 1] + r.y] = s.y;
    csr[off4[d.z * 4 + 2] + r.z] = s.z;
    csr[off4[d.w * 4 + 3] + r.w] = s.w;
}

// ---- preprocessing ---------------------------------------------------------
// [0,nbZ): zero off4 | [nbZ,nbZ+192): wconv 3 matrices (m=0 computes
// Wc=W_in@Ws0 on the fly) | [nbZ+192]: bc = b_in@Ws0.   (xconv deleted: R16)
__global__ __launch_bounds__(256) void k_pre(const float* __restrict__ W_in,
                                             const float* __restrict__ Ws,
                                             const float* __restrict__ b_in,
                                             ushort* __restrict__ Wf,
                                             float* __restrict__ bc,
                                             int* __restrict__ off4,
                                             int N, int nbZ) {
    int bid = blockIdx.x;
    if (bid < nbZ) {
        int i = bid * 256 + threadIdx.x;
        if (i < N * 4) off4[i] = 0;
    } else if (bid < nbZ + 192) {
        int idx = (bid - nbZ) * 256 + threadIdx.x;   // 3 * 16384
        int m = idx >> 14;
        int e = idx & 16383;
        int k = e >> 7, col = e & 127;
        float w;
        if (m == 0) {
            // Wc[k][col] = sum_j W_in[k][j] * Ws0[j][col]
            w = 0.f;
            #pragma unroll 8
            for (int j = 0; j < 128; ++j)
                w = fmaf(W_in[k * 128 + j], Ws[j * 128 + col], w);
        } else {
            w = Ws[m * 16384 + k * 128 + col];
        }
        ushort hi = f2bf(w);
        ushort lo = f2bf(w - bf2f(hi));
        int ks = k >> 5, lk = (k >> 3) & 3, j = k & 7;
        int ct = col >> 4, lane = lk * 16 + (col & 15);
        int o = m * 32768 + (ks * 8 + ct) * 512 + lane * 8 + j;
        Wf[o] = hi;
        Wf[o + 16384] = lo;
    } else {
        int col = threadIdx.x;
        if (col < 128) {
            float v = 0.f;
            #pragma unroll 8
            for (int j = 0; j < 128; ++j)
                v = fmaf(b_in[j], Ws[j * 128 + col], v);
            bc[col] = v;
        }
    }
}

// ---- MFMA GEMM -------------------------------------------------------------
// xwb[slice][M][64] = bf16(((A) @ W + bias) * scale), 3-term bf16 split.
// L0=1: A comes from x (fp32), split to hi/lo in registers.
// L0=0: A comes from hh/hl (pre-split bf16 pair).
// Col-half = bid&1 (block-level -> writer XCD parity == agg slice parity).
template<int L0>
__global__ __launch_bounds__(256) void k_mgemm(const ushort* Ahi, const ushort* Alo,
                                               const float* __restrict__ xf,
                                               const ushort* __restrict__ Wf,
                                               const float* __restrict__ bias,
                                               const float* __restrict__ scale,
                                               ushort* xwb, int M) {
    int l = threadIdx.x & 63;
    int ch = blockIdx.x & 1;
    int strip = (blockIdx.x >> 1) * 4 + (threadIdx.x >> 6);
    int r0 = strip * 16;
    int lr = l & 15, lk = l >> 4;
    int ar = r0 + lr; if (ar >= M) ar = M - 1;

    s8v ah0, ah1, ah2, ah3, al0, al1, al2, al3;
    if (L0) {
        const float* xr = xf + (long long)ar * HDIM + lk * 8;
        split8(*(const float4*)(xr),      *(const float4*)(xr + 4),  ah0, al0);
        split8(*(const float4*)(xr + 32), *(const float4*)(xr + 36), ah1, al1);
        split8(*(const float4*)(xr + 64), *(const float4*)(xr + 68), ah2, al2);
        split8(*(const float4*)(xr + 96), *(const float4*)(xr + 100), ah3, al3);
    } else {
        ah0 = *(const s8v*)(Ahi + (long long)ar * HDIM + lk * 8);
        ah1 = *(const s8v*)(Ahi + (long long)ar * HDIM + lk * 8 + 32);
        ah2 = *(const s8v*)(Ahi + (long long)ar * HDIM + lk * 8 + 64);
        ah3 = *(const s8v*)(Ahi + (long long)ar * HDIM + lk * 8 + 96);
        al0 = *(const s8v*)(Alo + (long long)ar * HDIM + lk * 8);
        al1 = *(const s8v*)(Alo + (long long)ar * HDIM + lk * 8 + 32);
        al2 = *(const s8v*)(Alo + (long long)ar * HDIM + lk * 8 + 64);
        al3 = *(const s8v*)(Alo + (long long)ar * HDIM + lk * 8 + 96);
    }

    f4v acc[4];
    #pragma unroll
    for (int c = 0; c < 4; ++c) acc[c] = (f4v){0.f, 0.f, 0.f, 0.f};

#define KSTEP(AH, AL, ksi)                                                          \
    {                                                                               \
        const ushort* wb = Wf + ((ksi) * 8 + ch * 4) * 512 + l * 8;                 \
        _Pragma("unroll")                                                           \
        for (int c = 0; c < 4; ++c) {                                               \
            s8v bh = *(const s8v*)(wb + c * 512);                                   \
            s8v bl = *(const s8v*)(wb + 16384 + c * 512);                           \
            acc[c] = __builtin_amdgcn_mfma_f32_16x16x32_bf16(AH, bh, acc[c], 0,0,0);\
            acc[c] = __builtin_amdgcn_mfma_f32_16x16x32_bf16(AH, bl, acc[c], 0,0,0);\
            acc[c] = __builtin_amdgcn_mfma_f32_16x16x32_bf16(AL, bh, acc[c], 0,0,0);\
        }                                                                           \
    }
    KSTEP(ah0, al0, 0)
    KSTEP(ah1, al1, 1)
    KSTEP(ah2, al2, 2)
    KSTEP(ah3, al3, 3)
#undef KSTEP

    if (r0 >= M) return;
    float bbv[4], sc[4];
    #pragma unroll
    for (int c = 0; c < 4; ++c) bbv[c] = bias ? bias[(ch * 4 + c) * 16 + lr] : 0.f;
    #pragma unroll
    for (int j = 0; j < 4; ++j) sc[j] = scale[r0 + lk * 4 + j];

    #pragma unroll
    for (int c = 0; c < 4; ++c) {
        #pragma unroll
        for (int j = 0; j < 4; ++j) {
            int row = r0 + lk * 4 + j;
            if (row >= M) continue;
            float o = (acc[c][j] + bbv[c]) * sc[j];
            int cc = c * 16 + lr;   // col within 64-col slice ch
            xwb[((long long)ch * M + row) * 64 + cc] = f2bf(o);
        }
    }
}

// ---- aggregation (L2-sliced + warm-up) -------------------------------------
// xwb [sl][row][64], 2.5MB/slice; slice = blockIdx&1 -> XCD parity.
// Warm-up streams the slice linearly (asm-kept-alive) so cross-XCD dirty-line
// first-touches happen at streaming rate. Quarter-wave edges (q=edge slot,
// t=col group), uint2 payload, 32-edge unroll, named int4 scalars,
// shfl_xor(16,32) reduce. LAST: fp32 d_out; else bf16 hi/lo split pair.
template<int LAST>
__global__ __launch_bounds__(256) void k_agg(const int* __restrict__ off4,
                                             const int* __restrict__ csr,
                                             const float* __restrict__ dis,
                                             const ushort* __restrict__ xwb,
                                             const float* __restrict__ b,
                                             float* __restrict__ outf,
                                             ushort* __restrict__ outhi,
                                             ushort* __restrict__ outlo, int N) {
    int lane = threadIdx.x & 63;
    int wv = threadIdx.x >> 6;
    int t = lane & 15, q = lane >> 4;
    int sl = blockIdx.x & 1;
    const ushort* xs = xwb + (long long)sl * N * 64;

    {   // L2 warm-up: 256 blocks per XCD share one slice; each streams 1/256
        int lb = blockIdx.x >> 3;                  // XCD-local block idx 0..255
        const float4* p4 = (const float4*)xs;      // N*8 float4 per slice
        int tot = N * 8;
        int chunk = (tot + 255) >> 8;
        int lo = lb * chunk;
        int hi = lo + chunk; if (hi > tot) hi = tot;
        float acc = 0.f;
        for (int i = lo + (int)threadIdx.x; i < hi; i += 256) {
            float4 u = p4[i];
            acc += (u.x + u.y) + (u.z + u.w);
        }
        asm volatile("" :: "v"(acc));              // keep loads alive (rule #17)
    }

    int v0 = (blockIdx.x >> 1) * 4 + wv;
    int vstride = (gridDim.x >> 1) * 4;

    float4 bb = ((const float4*)(b + sl * 64))[t];   // cols 4t..4t+3

#define GATH(sidx)                                                          \
    {                                                                       \
        uint2 u = *(const uint2*)(xs + (long long)(sidx) * 64 + (t << 2));  \
        ax += bf2f((ushort)u.x); ay += bf2f((ushort)(u.x >> 16));           \
        az += bf2f((ushort)u.y); aw += bf2f((ushort)(u.y >> 16));           \
    }
#define SEL(c) (q == 0 ? (c).x : q == 1 ? (c).y : q == 2 ? (c).z : (c).w)

    for (int v = v0; v < N; v += vstride) {
        int start = off4[v << 2];
        int end   = off4[(v << 2) + 4];
        float dv = dis[v];

        float ax = 0.f, ay = 0.f, az = 0.f, aw = 0.f;
        if (q == 0) GATH(v);                         // self term

        int i = start;
        for (; i + 32 <= end; i += 32) {
            int ib = __builtin_amdgcn_readfirstlane(i);
            int4 c0 = *(const int4*)(csr + ib);
            int4 c1 = *(const int4*)(csr + ib + 4);
            int4 c2 = *(const int4*)(csr + ib + 8);
            int4 c3 = *(const int4*)(csr + ib + 12);
            int4 c4 = *(const int4*)(csr + ib + 16);
            int4 c5 = *(const int4*)(csr + ib + 20);
            int4 c6 = *(const int4*)(csr + ib + 24);
            int4 c7 = *(const int4*)(csr + ib + 28);
            int s0 = SEL(c0), s1 = SEL(c1), s2 = SEL(c2), s3 = SEL(c3);
            int s4 = SEL(c4), s5 = SEL(c5), s6 = SEL(c6), s7 = SEL(c7);
            GATH(s0); GATH(s1); GATH(s2); GATH(s3);
            GATH(s4); GATH(s5); GATH(s6); GATH(s7);
        }
        if (i + 16 <= end) {
            int ib = __builtin_amdgcn_readfirstlane(i);
            int4 c0 = *(const int4*)(csr + ib);
            int4 c1 = *(const int4*)(csr + ib + 4);
            int4 c2 = *(const int4*)(csr + ib + 8);
            int4 c3 = *(const int4*)(csr + ib + 12);
            int s0 = SEL(c0), s1 = SEL(c1), s2 = SEL(c2), s3 = SEL(c3);
            GATH(s0); GATH(s1); GATH(s2); GATH(s3);
            i += 16;
        }
        if (i + 8 <= end) {
            int ib = __builtin_amdgcn_readfirstlane(i);
            int4 c0 = *(const int4*)(csr + ib);
            int4 c1 = *(const int4*)(csr + ib + 4);
            int s0 = SEL(c0), s1 = SEL(c1);
            GATH(s0); GATH(s1);
            i += 8;
        }
        if (i + 4 <= end) {
            int ib = __builtin_amdgcn_readfirstlane(i);
            int4 c0 = *(const int4*)(csr + ib);
            int s0 = SEL(c0);
            GATH(s0);
            i += 4;
        }
        {   // remainder 0..3 edges: one predicated round
            int r = end - i;
            if (q < r) {
                int s = csr[__builtin_amdgcn_readfirstlane(i) + q];
                GATH(s);
            }
        }

        ax += __shfl_xor(ax, 16); ax += __shfl_xor(ax, 32);
        ay += __shfl_xor(ay, 16); ay += __shfl_xor(ay, 32);
        az += __shfl_xor(az, 16); az += __shfl_xor(az, 32);
        aw += __shfl_xor(aw, 16); aw += __shfl_xor(aw, 32);

        if (q == 0) {
            float ox = fmaxf(fmaf(dv, ax, bb.x), 0.f);
            float oy = fmaxf(fmaf(dv, ay, bb.y), 0.f);
            float oz = fmaxf(fmaf(dv, az, bb.z), 0.f);
            float ow = fmaxf(fmaf(dv, aw, bb.w), 0.f);
            long long oidx = (long long)v * HDIM + sl * 64 + (t << 2);
            if (LAST) {
                *(float4*)(outf + oidx) = make_float4(ox, oy, oz, ow);
            } else {
                ushort h0 = f2bf(ox), h1 = f2bf(oy), h2 = f2bf(oz), h3 = f2bf(ow);
                uint2 ph, pl;
                ph.x = (uint)h0 | ((uint)h1 << 16);
                ph.y = (uint)h2 | ((uint)h3 << 16);
                pl.x = (uint)f2bf(ox - bf2f(h0)) | ((uint)f2bf(oy - bf2f(h1)) << 16);
                pl.y = (uint)f2bf(oz - bf2f(h2)) | ((uint)f2bf(ow - bf2f(h3)) << 16);
                *(uint2*)(outhi + oidx) = ph;
                *(uint2*)(outlo + oidx) = pl;
            }
        }
    }
#undef GATH
#undef SEL
}

extern "C" void kernel_launch(void* const* d_in, const int* in_sizes, int n_in,
                              void* d_out, int out_size, void* d_ws, size_t ws_size,
                              hipStream_t stream) {
    const float* x    = (const float*)d_in[0];
    const int*   ei   = (const int*)d_in[1];   // [2, E]: first E = src, next E = dst
    const float* W_in = (const float*)d_in[2];
    const float* b_in = (const float*)d_in[3];
    const float* Ws   = (const float*)d_in[4]; // [3,128,128]
    const float* bs   = (const float*)d_in[5]; // [3,128]

    const int N = in_sizes[0] / HDIM;
    const int E = in_sizes[1] / 2;
    const int* src = ei;
    const int* dst = ei + E;

    float*  dis  = (float*)d_ws;                     // N floats
    int*    off4 = (int*)(dis + N);                  // 4N+4 ints (excl prefix)
    int*    csr  = off4 + 4 * N + 4;                 // E ints (first ~80 = scan bsums, transient)
    int*    rank = csr + E;                          // E ints
    ushort* hh   = (ushort*)(rank + E);              // N*128 bf16 (h hi, row-major)
    ushort* hl   = hh + (long long)N * HDIM;         // N*128 bf16 (h lo, row-major)
    ushort* xwb  = hl + (long long)N * HDIM;         // [2][N][64] bf16, dis-prescaled
    float*  bc   = (float*)(xwb + (long long)2 * N * 64); // 128 floats (b_in@Ws0)
    ushort* Wf   = (ushort*)d_out;                   // 3*64KB scratch, overwritten by last agg

    int nbZ     = (4 * N + 255) / 256;
    int nb_E4   = (E / 4 + 255) / 256;
    int nb_scan = (4 * N + 1023) / 1024;
    int strips  = (N + 15) / 16;
    int nb_mg   = 2 * ((strips + 3) / 4);
    int nb_pre  = nbZ + 192 + 1;
    int nb_agg  = 2048;

    // preprocessing: zero off4 | Wc/W1/W2 fragments | bc
    k_pre<<<nb_pre, 256, 0, stream>>>(W_in, Ws, b_in, Wf, bc, off4, N, nbZ);

    // CSR build + dis: count(+rank) -> scan -> atomic-free fill
    k_count   <<<nb_E4,   256, 0, stream>>>(dst, off4, rank, E / 4);
    k_scan_blk<<<nb_scan, 256, 0, stream>>>(off4, dis, csr, N);
    k_scan_add<<<nb_scan, 256, 0, stream>>>(off4, csr, N, E);
    k_fill    <<<nb_E4,   256, 0, stream>>>(src, dst, off4, rank, csr, E / 4);

    for (int layer = 0; layer < 3; ++layer) {
        const ushort* Wfm = Wf + (long long)layer * 32768;
        const float* b = bs + (long long)layer * HDIM;
        if (layer == 0)
            k_mgemm<1><<<nb_mg, 256, 0, stream>>>(nullptr, nullptr, x, Wfm,
                                                  bc, dis, xwb, N);
        else
            k_mgemm<0><<<nb_mg, 256, 0, stream>>>(hh, hl, nullptr, Wfm,
                                                  nullptr, dis, xwb, N);
        if (layer == 2)
            k_agg<1><<<nb_agg, 256, 0, stream>>>(off4, csr, dis, xwb, b,
                                                 (float*)d_out, nullptr, nullptr, N);
        else
            k_agg<0><<<nb_agg, 256, 0, stream>>>(off4, csr, dis, xwb, b,
                                                 nullptr, hh, hl, N);
    }
}